// Round 15
// baseline (395.741 us; speedup 1.0000x reference)
//
#include <hip/hip_runtime.h>
#include <hip/hip_bf16.h>

typedef unsigned short u16;
using f32x4  = __attribute__((ext_vector_type(4))) float;
using bf16x8 = __attribute__((ext_vector_type(8))) short;

typedef __attribute__((address_space(1))) const void global_cvoid;
typedef __attribute__((address_space(3))) void lds_void;

__device__ __forceinline__ void async16(const u16* g, u16* l) {
    // direct global->LDS DMA, 16B per lane, LDS dest = wave-uniform base + lane*16
    __builtin_amdgcn_global_load_lds((global_cvoid*)g, (lds_void*)l, 16, 0, 0);
}

__device__ __forceinline__ u16 f2bf(float f) {
    union { float f; unsigned u; } cv; cv.f = f;
    unsigned r = cv.u + 0x7fff + ((cv.u >> 16) & 1);   // RNE
    return (u16)(r >> 16);
}

// truncating bf16 cast (1 op) — attention P values only (P bounded by 2^8:
// verified r9/r10/r12/r13/r14; larger P ranges FAIL — r11 empirical, do not retry)
__device__ __forceinline__ u16 f2bf_rz(float f) {
    union { float f; unsigned u; } cv; cv.f = f;
    return (u16)(cv.u >> 16);
}

// 16-lane-row max on the VALU pipe (DPP), not the LDS pipe
__device__ __forceinline__ float dppmax16(float x) {
    union { float f; int i; } c, o;
    c.f = x;
    o.i = __builtin_amdgcn_update_dpp(0, c.i, 0xB1,  0xF, 0xF, true); c.f = fmaxf(c.f, o.f);
    o.i = __builtin_amdgcn_update_dpp(0, c.i, 0x4E,  0xF, 0xF, true); c.f = fmaxf(c.f, o.f);
    o.i = __builtin_amdgcn_update_dpp(0, c.i, 0x141, 0xF, 0xF, true); c.f = fmaxf(c.f, o.f);
    o.i = __builtin_amdgcn_update_dpp(0, c.i, 0x140, 0xF, 0xF, true); c.f = fmaxf(c.f, o.f);
    return c.f;
}

// ---------------- cast fp32 -> bf16 ----------------
__global__ __launch_bounds__(256) void cast_kernel(const float* __restrict__ src,
                                                   u16* __restrict__ dst, int n4) {
    int i = blockIdx.x * blockDim.x + threadIdx.x;
    int st = gridDim.x * blockDim.x;
    for (; i < n4; i += st) {
        float4 v = ((const float4*)src)[i];
        ushort4 o;
        o.x = f2bf(v.x); o.y = f2bf(v.y); o.z = f2bf(v.z); o.w = f2bf(v.w);
        ((ushort4*)dst)[i] = o;
    }
}

// ---------------- transpose + cast: fp32 [R][C] -> bf16 [C][R] ----------------
__global__ __launch_bounds__(256) void wtrans_kernel(const float* __restrict__ src,
                                                     u16* __restrict__ dst, int R, int C) {
    __shared__ float tile[64][68];
    int ct = blockIdx.x, rt = blockIdx.y;
    int t = threadIdx.x;
    int r = t >> 2;
    const float* s = src + (size_t)(rt * 64 + r) * C + ct * 64;
#pragma unroll
    for (int jj = 0; jj < 4; ++jj) {
        int c4 = (t & 3) + jj * 4;
        float4 v = *(const float4*)(s + c4 * 4);
        *(float4*)&tile[r][c4 * 4] = v;
    }
    __syncthreads();
    int od = t >> 2;
    u16* d = dst + (size_t)(ct * 64 + od) * R + rt * 64;
#pragma unroll
    for (int jj = 0; jj < 4; ++jj) {
        int c4 = (t & 3) + jj * 4;
        ushort4 v;
        v.x = f2bf(tile[c4 * 4 + 0][od]);
        v.y = f2bf(tile[c4 * 4 + 1][od]);
        v.z = f2bf(tile[c4 * 4 + 2][od]);
        v.w = f2bf(tile[c4 * 4 + 3][od]);
        *(ushort4*)(d + c4 * 4) = v;
    }
}

// ---------------- 128x128 bf16 GEMM (m97 structure) — used for GEMM2 only ----------------
template<bool OUT_F32>
__global__ __launch_bounds__(256, 2)
void gemm_bt_kernel(const u16* __restrict__ A, const u16* __restrict__ BT,
                    void* __restrict__ Cout, const float* __restrict__ bias,
                    u16* __restrict__ VTout,
                    int M, int N, int K) {
    __shared__ u16 lA[128 * 64];
    __shared__ u16 lB[128 * 64];
    const int t = threadIdx.x;
    const int w = t >> 6, lane = t & 63;
    const int nbx = N >> 7;
    const int nwg = gridDim.x;
    int bid = blockIdx.x;
    int cpx = nwg >> 3;
    int swz = (bid & 7) * cpx + (bid >> 3);
    const int bx = swz % nbx;
    const int by = swz / nbx;
    const size_t m0 = (size_t)by * 128, n0 = (size_t)bx * 128;

    const int lr = lane >> 3;
    const int lc = (lane & 7) * 8;
    const int wr = (w >> 1) * 64, wc = (w & 1) * 64;

    f32x4 acc[4][4] = {};

    for (int kk = 0; kk < K; kk += 64) {
        __syncthreads();
#pragma unroll
        for (int i = 0; i < 4; ++i) {
            int rr = (w * 4 + i) * 8 + lr;
            async16(A  + (m0 + rr) * (size_t)K + kk + lc, &lA[(w * 4 + i) * 512]);
            async16(BT + (n0 + rr) * (size_t)K + kk + lc, &lB[(w * 4 + i) * 512]);
        }
        __syncthreads();
#pragma unroll
        for (int ks = 0; ks < 2; ++ks) {
            bf16x8 af[4], bfv[4];
#pragma unroll
            for (int m = 0; m < 4; ++m)
                af[m] = *(const bf16x8*)&lA[(wr + m * 16 + (lane & 15)) * 64 + ks * 32 + (lane >> 4) * 8];
#pragma unroll
            for (int n = 0; n < 4; ++n)
                bfv[n] = *(const bf16x8*)&lB[(wc + n * 16 + (lane & 15)) * 64 + ks * 32 + (lane >> 4) * 8];
#pragma unroll
            for (int m = 0; m < 4; ++m)
#pragma unroll
                for (int n = 0; n < 4; ++n)
                    acc[m][n] = __builtin_amdgcn_mfma_f32_16x16x32_bf16(af[m], bfv[n], acc[m][n], 0, 0, 0);
        }
    }

    const int r0 = (lane >> 4) * 4;
    const int cl = lane & 15;
    if constexpr (OUT_F32) {
        float* C = (float*)Cout;
#pragma unroll
        for (int m = 0; m < 4; ++m) {
            size_t row = m0 + wr + m * 16 + r0;
#pragma unroll
            for (int n = 0; n < 4; ++n) {
                size_t col = n0 + wc + n * 16 + cl;
                float bv = bias[col];
#pragma unroll
                for (int r = 0; r < 4; ++r)
                    C[(row + r) * (size_t)N + col] = acc[m][n][r] + bv;
            }
        }
    } else {
        u16* C = (u16*)Cout;
#pragma unroll
        for (int m = 0; m < 4; ++m) {
            size_t row = m0 + wr + m * 16 + r0;
#pragma unroll
            for (int n = 0; n < 4; ++n) {
                size_t col = n0 + wc + n * 16 + cl;
#pragma unroll
                for (int r = 0; r < 4; ++r)
                    C[(row + r) * (size_t)N + col] = f2bf(acc[m][n][r]);
            }
        }
    }
}

// ---------------- 256x256 pipelined GEMM v2 — m201-style fine phases ----------------
// vs r10/r14 ring (869 TF, MfmaUtil 38.7): same 4-slot ring + counted vmcnt
// (T4, proven race-free), but the K-half is split into TWO phases each ending
// in a raw-barrier + setprio'd 16-MFMA cluster (m196/m201's fine interleave —
// the documented +28-41% lever). P0: read 4 B-frags + 4 A-frags (m0-3), stage
// 2 loads; barrier; 16 MFMA. P1: read 4 A-frags (m4-7, B reused in-reg),
// stage 2 loads; barrier; 16 MFMA. Raw s_barrier keeps loads in flight.
// Waits: ONE vmcnt(4) per K-half at top (own-wave: kh's 4 loads oldest;
// kh+1's 4 in flight; never 0 until last iter) + barrier for cross-wave
// visibility. MFMA order per acc unchanged -> bit-identical C vs r14.
__global__ __launch_bounds__(512, 2)
void gemm256_kernel(const u16* __restrict__ A, const u16* __restrict__ BT,
                    u16* __restrict__ Cout, u16* __restrict__ VTout,
                    int M, int N, int K) {
    __shared__ u16 lds[65536];                 // 131072 B: A-ring 64KB | B-ring 64KB
    u16* lA = lds;
    u16* lB = lds + 32768;

    const int t = threadIdx.x, w = t >> 6, l = t & 63;
    const int g = l >> 4, ql = l & 15;
    const int wm = w >> 2, wn = w & 3;          // 2M x 4N wave grid
    const int nbx = N >> 8;
    int bid = blockIdx.x;
    int cpx = gridDim.x >> 3;                   // grid % 8 == 0
    int swz = (bid & 7) * cpx + (bid >> 3);
    const int bx = swz % nbx, by = swz / nbx;
    const size_t m0 = (size_t)by * 256, n0 = (size_t)bx * 256;

    const u16* Ag = A  + m0 * (size_t)K;
    const u16* Bg = BT + n0 * (size_t)K;

    // staging: per K-half tile [256][32]: 1024 16B-chunks; thread does ch = t, t+512.
    // source col pre-swizzled: chunk c of row r holds global chunk c ^ ((r>>1)&3).
    unsigned soff[2];
#pragma unroll
    for (int i = 0; i < 2; ++i) {
        int ch = i * 512 + t;
        int r = ch >> 2, c = ch & 3;
        soff[i] = (unsigned)(r * K + (c ^ ((r >> 1) & 3)) * 8);
    }

    // pair i: one A-load + one B-load (2 per phase, 4 per K-half)
#define STAGE_PAIR(kh2, i) do {                                                    \
    int sl_ = (kh2) & 3;                                                           \
    async16(Ag + soff[i] + (unsigned)(kh2) * 32u, lA + sl_ * 8192 + ((i) * 512 + w * 64) * 8); \
    async16(Bg + soff[i] + (unsigned)(kh2) * 32u, lB + sl_ * 8192 + ((i) * 512 + w * 64) * 8); \
    } while (0)
#define STAGE_FULL(kh2) do { STAGE_PAIR(kh2, 0); STAGE_PAIR(kh2, 1); } while (0)

    STAGE_FULL(0); STAGE_FULL(1);              // prologue: 2 K-halves in flight (8 loads)

    f32x4 acc[8][4] = {};
    const int cswz = (g ^ ((ql >> 1) & 3)) * 8;
    const int arow = wm * 128 + ql;
    const int brow = wn * 64 + ql;

    const int KH = K >> 5;                     // K-halves of 32
#pragma unroll 1
    for (int kh = 0; kh < KH; ++kh) {
        if (kh < KH - 1) asm volatile("s_waitcnt vmcnt(4)" ::: "memory");
        else             asm volatile("s_waitcnt vmcnt(0)" ::: "memory");
        __builtin_amdgcn_s_barrier();          // slot kh visible across waves
        const u16* sA = lA + (kh & 3) * 8192;
        const u16* sB = lB + (kh & 3) * 8192;

        bf16x8 fb[4], fa[4];
        // ---- phase 0: B + A(m0-3) reads, stage pair0, barrier, 16 MFMA ----
#pragma unroll
        for (int n = 0; n < 4; ++n)
            fb[n] = *(const bf16x8*)&sB[(brow + n * 16) * 32 + cswz];
#pragma unroll
        for (int m = 0; m < 4; ++m)
            fa[m] = *(const bf16x8*)&sA[(arow + m * 16) * 32 + cswz];
        if (kh + 2 < KH) STAGE_PAIR(kh + 2, 0);
        __builtin_amdgcn_s_barrier();
        __builtin_amdgcn_s_setprio(1);
#pragma unroll
        for (int m = 0; m < 4; ++m)
#pragma unroll
            for (int n = 0; n < 4; ++n)
                acc[m][n] = __builtin_amdgcn_mfma_f32_16x16x32_bf16(fa[m], fb[n], acc[m][n], 0, 0, 0);
        __builtin_amdgcn_s_setprio(0);

        // ---- phase 1: A(m4-7) reads, stage pair1, barrier, 16 MFMA ----
#pragma unroll
        for (int m = 0; m < 4; ++m)
            fa[m] = *(const bf16x8*)&sA[(arow + (m + 4) * 16) * 32 + cswz];
        if (kh + 2 < KH) STAGE_PAIR(kh + 2, 1);
        __builtin_amdgcn_s_barrier();
        __builtin_amdgcn_s_setprio(1);
#pragma unroll
        for (int m = 0; m < 4; ++m)
#pragma unroll
            for (int n = 0; n < 4; ++n)
                acc[m + 4][n] = __builtin_amdgcn_mfma_f32_16x16x32_bf16(fa[m], fb[n], acc[m + 4][n], 0, 0, 0);
        __builtin_amdgcn_s_setprio(0);
    }

    // epilogue (C/D: row = g*4 + r, col = ql per 16x16 fragment)
    const int r0 = g * 4;
    int tok0 = (int)(m0 % 3072);               // 256-tile stays within one third
    if (tok0 >= 2048) {
        // V third -> transposed VT[(b*16+h)*192 + ch][tok]
        int b = (int)(m0 / 3072);
#pragma unroll
        for (int m = 0; m < 8; ++m) {
            int tok = tok0 - 2048 + wm * 128 + m * 16 + r0;
#pragma unroll
            for (int n = 0; n < 4; ++n) {
                int col = (int)n0 + wn * 64 + n * 16 + ql;
                int h = col / 192, ch = col % 192;
                ushort4 v;
                v.x = f2bf(acc[m][n][0]);
                v.y = f2bf(acc[m][n][1]);
                v.z = f2bf(acc[m][n][2]);
                v.w = f2bf(acc[m][n][3]);
                *(ushort4*)(VTout + ((size_t)(b * 16 + h) * 192 + ch) * 1024 + tok) = v;
            }
        }
    } else {
        float qs = (tok0 < 1024) ? 0.1803368801111f : 1.0f;  // Q third: fold 0.125*log2(e)
#pragma unroll
        for (int m = 0; m < 8; ++m) {
            size_t row = m0 + wm * 128 + m * 16 + r0;
#pragma unroll
            for (int n = 0; n < 4; ++n) {
                size_t col = n0 + wn * 64 + n * 16 + ql;
#pragma unroll
                for (int r = 0; r < 4; ++r)
                    Cout[(row + r) * (size_t)N + col] = f2bf(acc[m][n][r] * qs);
            }
        }
    }
#undef STAGE_PAIR
#undef STAGE_FULL
}

// ---------------- flash attention v10 (r14 version, unchanged) ----------------
__global__ __launch_bounds__(256, 2)
void attn_kernel(const u16* __restrict__ QKV, const u16* __restrict__ VT,
                 u16* __restrict__ comb) {
    __shared__ u16 lds[40960];                 // 81920 B: K-ring | V-ring | P
    u16* lK = lds;                             // 3 x [32][192] swz (6144 u16 each)
    u16* lV = lds + 18432;                     // 3 x [192][32] swz (6144 u16 each)
    u16* lP = lds + 36864;                     // 4 waves x [32][32] chunk-XOR (1024 u16 each)

    const int t = threadIdx.x, w = t >> 6, lane = t & 63;
    const int g = lane >> 4, ql = lane & 15;
    const int bid = blockIdx.x;                // 1024 blocks
    const int gid = (bid & 7) * 128 + (bid >> 3);   // XCD-chunked
    const int bh = gid >> 3, qt = gid & 7;
    const int b = bh >> 4, h = bh & 15;

    const u16* Qg  = QKV + ((size_t)(b * 3072 + qt * 128 + w * 32)) * 3072 + h * 192;
    const u16* Kg  = QKV + ((size_t)(b * 3072 + 1024)) * 3072 + h * 192;
    const u16* VTg = VT + (size_t)bh * 192 * 1024;

    unsigned koff[3], voff[3];
#pragma unroll
    for (int i = 0; i < 3; ++i) {
        int ch = i * 256 + t;
        int kr = ch / 24, kc = ch % 24;
        koff[i] = kr * 3072 + (kc ^ (kr & 7)) * 8;
        int vr = ch >> 2, vc = ch & 3;
        voff[i] = vr * 1024 + (vc ^ ((vr >> 1) & 3)) * 8;   // period-8 swizzle
    }

#define STAGE_KV(kt) do {                                                         \
    int sl_ = (kt) % 3;                                                           \
    _Pragma("unroll")                                                             \
    for (int i = 0; i < 3; ++i) {                                                 \
        async16(Kg + koff[i] + (unsigned)(kt) * 98304u, lK + sl_ * 6144 + (i * 256 + w * 64) * 8); \
        async16(VTg + voff[i] + (unsigned)(kt) * 32u,   lV + sl_ * 6144 + (i * 256 + w * 64) * 8); \
    } } while (0)

    STAGE_KV(0);
    STAGE_KV(1);                               // 2-deep prefetch in flight

    bf16x8 aq[2][6];
#pragma unroll
    for (int rg = 0; rg < 2; ++rg)
#pragma unroll
        for (int cs = 0; cs < 6; ++cs)
            aq[rg][cs] = *(const bf16x8*)(Qg + (size_t)(rg * 16 + ql) * 3072
                                             + cs * 32 + g * 8);

    bf16x8 vone;
#pragma unroll
    for (int j = 0; j < 8; ++j) vone[j] = (short)0x3F80;

    f32x4 acc_o[2][12] = {};
    f32x4 acc_l[2] = {};                       // per-row lsum via ones-MFMA
    float m2[2] = {-1e30f, -1e30f};            // per-4-row-group running max
    u16* lPw = &lP[w * 1024];                  // [32][32], 16B-chunk XOR by (q>>2)&3
    const int pswz = (ql >> 2) & 3;

#pragma unroll 1
    for (int it = 0; it < 32; ++it) {
        if (it != 31) asm volatile("s_waitcnt vmcnt(6)" ::: "memory");
        else          asm volatile("s_waitcnt vmcnt(0)" ::: "memory");
        __builtin_amdgcn_s_barrier();
        if (it < 30) STAGE_KV(it + 2);

        const u16* sK = lK + (it % 3) * 6144;
        const u16* sV = lV + (it % 3) * 6144;

        f32x4 s[2][2] = {};
        __builtin_amdgcn_s_setprio(1);
#pragma unroll
        for (int kf = 0; kf < 2; ++kf) {
            const int krow = kf * 16 + ql;
#pragma unroll
            for (int cs = 0; cs < 6; ++cs) {
                bf16x8 bk = *(const bf16x8*)&sK[krow * 192 + ((cs * 4 + g) ^ (krow & 7)) * 8];
                s[0][kf] = __builtin_amdgcn_mfma_f32_16x16x32_bf16(aq[0][cs], bk, s[0][kf], 0, 0, 0);
                s[1][kf] = __builtin_amdgcn_mfma_f32_16x16x32_bf16(aq[1][cs], bk, s[1][kf], 0, 0, 0);
            }
        }
        __builtin_amdgcn_s_setprio(0);

#pragma unroll
        for (int rg = 0; rg < 2; ++rg) {
            float m = s[rg][0][0];
#pragma unroll
            for (int kf = 0; kf < 2; ++kf)
#pragma unroll
                for (int r = 0; r < 4; ++r) m = fmaxf(m, s[rg][kf][r]);
            float mx = dppmax16(m);
            bool need = mx > m2[rg] + 8.f;
            if (__any((int)need)) {
                float mn = fmaxf(m2[rg], mx);
                float fac = exp2f(m2[rg] - mn);
                m2[rg] = mn;
                acc_l[rg] *= fac;
#pragma unroll
                for (int df = 0; df < 12; ++df) acc_o[rg][df] *= fac;
            }
#pragma unroll
            for (int r = 0; r < 4; ++r) {
                int q = rg * 16 + g * 4 + r;
#pragma unroll
                for (int kf = 0; kf < 2; ++kf) {
                    float p = exp2f(s[rg][kf][r] - m2[rg]);   // bounded by 2^8
                    lPw[q * 32 + ((kf * 16 + ql) ^ (g << 3))] = f2bf_rz(p);
                }
            }
        }

        __builtin_amdgcn_s_setprio(1);
        {
            bf16x8 pa0 = *(const bf16x8*)&lPw[ql * 32 + ((g ^ pswz) << 3)];
            bf16x8 pa1 = *(const bf16x8*)&lPw[(16 + ql) * 32 + ((g ^ pswz) << 3)];
            acc_l[0] = __builtin_amdgcn_mfma_f32_16x16x32_bf16(pa0, vone, acc_l[0], 0, 0, 0);
            acc_l[1] = __builtin_amdgcn_mfma_f32_16x16x32_bf16(pa1, vone, acc_l[1], 0, 0, 0);
#pragma unroll
            for (int df = 0; df < 12; ++df) {
                const int vrow = df * 16 + ql;
                bf16x8 bv = *(const bf16x8*)&sV[vrow * 32 + ((g ^ ((vrow >> 1) & 3)) << 3)];
                acc_o[0][df] = __builtin_amdgcn_mfma_f32_16x16x32_bf16(pa0, bv, acc_o[0][df], 0, 0, 0);
                acc_o[1][df] = __builtin_amdgcn_mfma_f32_16x16x32_bf16(pa1, bv, acc_o[1][df], 0, 0, 0);
            }
        }
        __builtin_amdgcn_s_setprio(0);
    }

    u16* dst = comb + ((size_t)(b * 1024 + qt * 128 + w * 32)) * 3072 + h * 192;
#pragma unroll
    for (int rg = 0; rg < 2; ++rg)
#pragma unroll
        for (int r = 0; r < 4; ++r) {
            int q = rg * 16 + g * 4 + r;
            float invl = 1.0f / acc_l[rg][r];
#pragma unroll
            for (int df = 0; df < 12; ++df)
                dst[(size_t)q * 3072 + df * 16 + ql] = f2bf(acc_o[rg][df][r] * invl);
        }
#undef STAGE_KV
}

// ---------------- host ----------------
extern "C" void kernel_launch(void* const* d_in, const int* in_sizes, int n_in,
                              void* d_out, int out_size, void* d_ws, size_t ws_size,
                              hipStream_t stream) {
    const float* X  = (const float*)d_in[0];   // [8,3072,1024]
    const float* W1 = (const float*)d_in[1];   // [1024,3072]
    const float* W2 = (const float*)d_in[2];   // [3072,1024]
    const float* Bb = (const float*)d_in[3];   // [1024]

    char* ws = (char*)d_ws;
    u16* Xb   = (u16*)(ws);                          // 50,331,648 B ; reused as comb
    u16* W1bT = (u16*)(ws + 50331648);               //  6,291,456 B  [3072][1024]
    u16* W2bT = (u16*)(ws + 56623104);               //  6,291,456 B  [1024][3072]
    u16* QKVb = (u16*)(ws + 62914560);               // 150,994,944 B [24576][3072] (V third unused)
    u16* VT   = (u16*)(ws + 213909504);              // 50,331,648 B  [128][192][1024]
    u16* comb = Xb;                                  // [8192][3072]

    cast_kernel<<<2048, 256, 0, stream>>>(X, Xb, (8 * 3072 * 1024) / 4);
    wtrans_kernel<<<dim3(3072 / 64, 1024 / 64), 256, 0, stream>>>(W1, W1bT, 1024, 3072);
    wtrans_kernel<<<dim3(1024 / 64, 3072 / 64), 256, 0, stream>>>(W2, W2bT, 3072, 1024);
    // GEMM1 (QKV): pipelined 256^2 kernel; V-third -> VT transposed, Q-third pre-scaled
    gemm256_kernel<<<(24576 / 256) * (3072 / 256), 512, 0, stream>>>(
        Xb, W1bT, QKVb, VT, 24576, 3072, 1024);
    attn_kernel<<<1024, 256, 0, stream>>>(QKVb, VT, comb);
    gemm_bt_kernel<true><<<(8192 / 128) * (1024 / 128), 256, 0, stream>>>(
        comb, W2bT, d_out, Bb, nullptr, 8192, 1024, 3072);
}

// Round 16
// 386.406 us; speedup vs baseline: 1.0242x; 1.0242x over previous
//
#include <hip/hip_runtime.h>
#include <hip/hip_bf16.h>

typedef unsigned short u16;
using f32x4  = __attribute__((ext_vector_type(4))) float;
using bf16x8 = __attribute__((ext_vector_type(8))) short;

typedef __attribute__((address_space(1))) const void global_cvoid;
typedef __attribute__((address_space(3))) void lds_void;

__device__ __forceinline__ void async16(const u16* g, u16* l) {
    // direct global->LDS DMA, 16B per lane, LDS dest = wave-uniform base + lane*16
    __builtin_amdgcn_global_load_lds((global_cvoid*)g, (lds_void*)l, 16, 0, 0);
}

__device__ __forceinline__ u16 f2bf(float f) {
    union { float f; unsigned u; } cv; cv.f = f;
    unsigned r = cv.u + 0x7fff + ((cv.u >> 16) & 1);   // RNE
    return (u16)(r >> 16);
}

// truncating bf16 cast (1 op) — attention P values only (P bounded by 2^8:
// verified r9/r10/r12/r13/r14; larger P ranges FAIL — r11 empirical, do not retry)
__device__ __forceinline__ u16 f2bf_rz(float f) {
    union { float f; unsigned u; } cv; cv.f = f;
    return (u16)(cv.u >> 16);
}

// 16-lane-row max on the VALU pipe (DPP), not the LDS pipe
__device__ __forceinline__ float dppmax16(float x) {
    union { float f; int i; } c, o;
    c.f = x;
    o.i = __builtin_amdgcn_update_dpp(0, c.i, 0xB1,  0xF, 0xF, true); c.f = fmaxf(c.f, o.f);
    o.i = __builtin_amdgcn_update_dpp(0, c.i, 0x4E,  0xF, 0xF, true); c.f = fmaxf(c.f, o.f);
    o.i = __builtin_amdgcn_update_dpp(0, c.i, 0x141, 0xF, 0xF, true); c.f = fmaxf(c.f, o.f);
    o.i = __builtin_amdgcn_update_dpp(0, c.i, 0x140, 0xF, 0xF, true); c.f = fmaxf(c.f, o.f);
    return c.f;
}

// ---------------- cast fp32 -> bf16 ----------------
__global__ __launch_bounds__(256) void cast_kernel(const float* __restrict__ src,
                                                   u16* __restrict__ dst, int n4) {
    int i = blockIdx.x * blockDim.x + threadIdx.x;
    int st = gridDim.x * blockDim.x;
    for (; i < n4; i += st) {
        float4 v = ((const float4*)src)[i];
        ushort4 o;
        o.x = f2bf(v.x); o.y = f2bf(v.y); o.z = f2bf(v.z); o.w = f2bf(v.w);
        ((ushort4*)dst)[i] = o;
    }
}

// ---------------- transpose + cast: fp32 [R][C] -> bf16 [C][R] ----------------
__global__ __launch_bounds__(256) void wtrans_kernel(const float* __restrict__ src,
                                                     u16* __restrict__ dst, int R, int C) {
    __shared__ float tile[64][68];
    int ct = blockIdx.x, rt = blockIdx.y;
    int t = threadIdx.x;
    int r = t >> 2;
    const float* s = src + (size_t)(rt * 64 + r) * C + ct * 64;
#pragma unroll
    for (int jj = 0; jj < 4; ++jj) {
        int c4 = (t & 3) + jj * 4;
        float4 v = *(const float4*)(s + c4 * 4);
        *(float4*)&tile[r][c4 * 4] = v;
    }
    __syncthreads();
    int od = t >> 2;
    u16* d = dst + (size_t)(ct * 64 + od) * R + rt * 64;
#pragma unroll
    for (int jj = 0; jj < 4; ++jj) {
        int c4 = (t & 3) + jj * 4;
        ushort4 v;
        v.x = f2bf(tile[c4 * 4 + 0][od]);
        v.y = f2bf(tile[c4 * 4 + 1][od]);
        v.z = f2bf(tile[c4 * 4 + 2][od]);
        v.w = f2bf(tile[c4 * 4 + 3][od]);
        *(ushort4*)(d + c4 * 4) = v;
    }
}

// ---------------- 128x128 bf16 GEMM (m97 structure) — used for GEMM2 only ----------------
template<bool OUT_F32>
__global__ __launch_bounds__(256, 2)
void gemm_bt_kernel(const u16* __restrict__ A, const u16* __restrict__ BT,
                    void* __restrict__ Cout, const float* __restrict__ bias,
                    u16* __restrict__ VTout,
                    int M, int N, int K) {
    __shared__ u16 lA[128 * 64];
    __shared__ u16 lB[128 * 64];
    const int t = threadIdx.x;
    const int w = t >> 6, lane = t & 63;
    const int nbx = N >> 7;
    const int nwg = gridDim.x;
    int bid = blockIdx.x;
    int cpx = nwg >> 3;
    int swz = (bid & 7) * cpx + (bid >> 3);
    const int bx = swz % nbx;
    const int by = swz / nbx;
    const size_t m0 = (size_t)by * 128, n0 = (size_t)bx * 128;

    const int lr = lane >> 3;
    const int lc = (lane & 7) * 8;
    const int wr = (w >> 1) * 64, wc = (w & 1) * 64;

    f32x4 acc[4][4] = {};

    for (int kk = 0; kk < K; kk += 64) {
        __syncthreads();
#pragma unroll
        for (int i = 0; i < 4; ++i) {
            int rr = (w * 4 + i) * 8 + lr;
            async16(A  + (m0 + rr) * (size_t)K + kk + lc, &lA[(w * 4 + i) * 512]);
            async16(BT + (n0 + rr) * (size_t)K + kk + lc, &lB[(w * 4 + i) * 512]);
        }
        __syncthreads();
#pragma unroll
        for (int ks = 0; ks < 2; ++ks) {
            bf16x8 af[4], bfv[4];
#pragma unroll
            for (int m = 0; m < 4; ++m)
                af[m] = *(const bf16x8*)&lA[(wr + m * 16 + (lane & 15)) * 64 + ks * 32 + (lane >> 4) * 8];
#pragma unroll
            for (int n = 0; n < 4; ++n)
                bfv[n] = *(const bf16x8*)&lB[(wc + n * 16 + (lane & 15)) * 64 + ks * 32 + (lane >> 4) * 8];
#pragma unroll
            for (int m = 0; m < 4; ++m)
#pragma unroll
                for (int n = 0; n < 4; ++n)
                    acc[m][n] = __builtin_amdgcn_mfma_f32_16x16x32_bf16(af[m], bfv[n], acc[m][n], 0, 0, 0);
        }
    }

    const int r0 = (lane >> 4) * 4;
    const int cl = lane & 15;
    if constexpr (OUT_F32) {
        float* C = (float*)Cout;
#pragma unroll
        for (int m = 0; m < 4; ++m) {
            size_t row = m0 + wr + m * 16 + r0;
#pragma unroll
            for (int n = 0; n < 4; ++n) {
                size_t col = n0 + wc + n * 16 + cl;
                float bv = bias[col];
#pragma unroll
                for (int r = 0; r < 4; ++r)
                    C[(row + r) * (size_t)N + col] = acc[m][n][r] + bv;
            }
        }
    } else {
        u16* C = (u16*)Cout;
#pragma unroll
        for (int m = 0; m < 4; ++m) {
            size_t row = m0 + wr + m * 16 + r0;
#pragma unroll
            for (int n = 0; n < 4; ++n) {
                size_t col = n0 + wc + n * 16 + cl;
#pragma unroll
                for (int r = 0; r < 4; ++r)
                    C[(row + r) * (size_t)N + col] = f2bf(acc[m][n][r]);
            }
        }
    }
}

// ---------------- 256x256 pipelined GEMM (T2+T4 ring, r14 version) — GEMM1/QKV ----------------
// REVERT of r15's fine-phase split (189 µs, MfmaUtil 35.9) back to the r14
// ring (178 µs, MfmaUtil 38.7, 0 conflicts, no spill). r15 post-mortem: the
// 2-barrier-per-K-half split is the m196 "coarse split" failure mode — the
// true m201 8-phase needs half-tile staging geometry not reconstructible
// from the catalog description; two attempts failed, do not retry blind.
__global__ __launch_bounds__(512, 2)
void gemm256_kernel(const u16* __restrict__ A, const u16* __restrict__ BT,
                    u16* __restrict__ Cout, u16* __restrict__ VTout,
                    int M, int N, int K) {
    __shared__ u16 lds[65536];                 // 131072 B: A-ring 64KB | B-ring 64KB
    u16* lA = lds;
    u16* lB = lds + 32768;

    const int t = threadIdx.x, w = t >> 6, l = t & 63;
    const int g = l >> 4, ql = l & 15;
    const int wm = w >> 2, wn = w & 3;          // 2M x 4N wave grid
    const int nbx = N >> 8;
    int bid = blockIdx.x;
    int cpx = gridDim.x >> 3;                   // grid % 8 == 0
    int swz = (bid & 7) * cpx + (bid >> 3);
    const int bx = swz % nbx, by = swz / nbx;
    const size_t m0 = (size_t)by * 256, n0 = (size_t)bx * 256;

    const u16* Ag = A  + m0 * (size_t)K;
    const u16* Bg = BT + n0 * (size_t)K;

    unsigned soff[2];
#pragma unroll
    for (int i = 0; i < 2; ++i) {
        int ch = i * 512 + t;
        int r = ch >> 2, c = ch & 3;
        soff[i] = (unsigned)(r * K + (c ^ ((r >> 1) & 3)) * 8);
    }

#define STAGE8(kh3) do {                                                           \
    int sl_ = (kh3) & 3;                                                           \
    _Pragma("unroll")                                                              \
    for (int i = 0; i < 2; ++i) {                                                  \
        async16(Ag + soff[i] + (unsigned)(kh3) * 32u, lA + sl_ * 8192 + (i * 512 + w * 64) * 8); \
        async16(Bg + soff[i] + (unsigned)(kh3) * 32u, lB + sl_ * 8192 + (i * 512 + w * 64) * 8); \
    } } while (0)

    STAGE8(0); STAGE8(1); STAGE8(2);           // prologue: 3 K-halves in flight

    f32x4 acc[8][4] = {};
    const int cswz = (g ^ ((ql >> 1) & 3)) * 8;
    const int arow = wm * 128 + ql;
    const int brow = wn * 64 + ql;

    auto phase = [&](int kh, int vm, bool st) {
        if (vm == 8)      asm volatile("s_waitcnt vmcnt(8)" ::: "memory");
        else if (vm == 4) asm volatile("s_waitcnt vmcnt(4)" ::: "memory");
        else              asm volatile("s_waitcnt vmcnt(0)" ::: "memory");
        __builtin_amdgcn_s_barrier();
        const u16* sA = lA + (kh & 3) * 8192;
        const u16* sB = lB + (kh & 3) * 8192;
        bf16x8 fa[8], fb[4];
#pragma unroll
        for (int m = 0; m < 8; ++m)
            fa[m] = *(const bf16x8*)&sA[(arow + m * 16) * 32 + cswz];
#pragma unroll
        for (int n = 0; n < 4; ++n)
            fb[n] = *(const bf16x8*)&sB[(brow + n * 16) * 32 + cswz];
        if (st) STAGE8(kh + 3);
        __builtin_amdgcn_s_setprio(1);
#pragma unroll
        for (int m = 0; m < 8; ++m)
#pragma unroll
            for (int n = 0; n < 4; ++n)
                acc[m][n] = __builtin_amdgcn_mfma_f32_16x16x32_bf16(fa[m], fb[n], acc[m][n], 0, 0, 0);
        __builtin_amdgcn_s_setprio(0);
    };

    const int KH = K >> 5;                     // K-halves of 32
#pragma unroll 1
    for (int kh = 0; kh < KH - 3; ++kh) phase(kh, 8, true);
    phase(KH - 3, 8, false);                   // tail: drain ring, vmcnt 8 -> 4 -> 0
    phase(KH - 2, 4, false);
    phase(KH - 1, 0, false);

    const int r0 = g * 4;
    int tok0 = (int)(m0 % 3072);               // 256-tile stays within one third
    if (tok0 >= 2048) {
        // V third -> transposed VT[(b*16+h)*192 + ch][tok]
        int b = (int)(m0 / 3072);
#pragma unroll
        for (int m = 0; m < 8; ++m) {
            int tok = tok0 - 2048 + wm * 128 + m * 16 + r0;
#pragma unroll
            for (int n = 0; n < 4; ++n) {
                int col = (int)n0 + wn * 64 + n * 16 + ql;
                int h = col / 192, ch = col % 192;
                ushort4 v;
                v.x = f2bf(acc[m][n][0]);
                v.y = f2bf(acc[m][n][1]);
                v.z = f2bf(acc[m][n][2]);
                v.w = f2bf(acc[m][n][3]);
                *(ushort4*)(VTout + ((size_t)(b * 16 + h) * 192 + ch) * 1024 + tok) = v;
            }
        }
    } else {
        float qs = (tok0 < 1024) ? 0.1803368801111f : 1.0f;  // Q third: fold 0.125*log2(e)
#pragma unroll
        for (int m = 0; m < 8; ++m) {
            size_t row = m0 + wm * 128 + m * 16 + r0;
#pragma unroll
            for (int n = 0; n < 4; ++n) {
                size_t col = n0 + wn * 64 + n * 16 + ql;
#pragma unroll
                for (int r = 0; r < 4; ++r)
                    Cout[(row + r) * (size_t)N + col] = f2bf(acc[m][n][r] * qs);
            }
        }
    }
#undef STAGE8
}

// ---------------- flash attention v10 (r14 version, unchanged) ----------------
__global__ __launch_bounds__(256, 2)
void attn_kernel(const u16* __restrict__ QKV, const u16* __restrict__ VT,
                 u16* __restrict__ comb) {
    __shared__ u16 lds[40960];                 // 81920 B: K-ring | V-ring | P
    u16* lK = lds;                             // 3 x [32][192] swz (6144 u16 each)
    u16* lV = lds + 18432;                     // 3 x [192][32] swz (6144 u16 each)
    u16* lP = lds + 36864;                     // 4 waves x [32][32] chunk-XOR (1024 u16 each)

    const int t = threadIdx.x, w = t >> 6, lane = t & 63;
    const int g = lane >> 4, ql = lane & 15;
    const int bid = blockIdx.x;                // 1024 blocks
    const int gid = (bid & 7) * 128 + (bid >> 3);   // XCD-chunked
    const int bh = gid >> 3, qt = gid & 7;
    const int b = bh >> 4, h = bh & 15;

    const u16* Qg  = QKV + ((size_t)(b * 3072 + qt * 128 + w * 32)) * 3072 + h * 192;
    const u16* Kg  = QKV + ((size_t)(b * 3072 + 1024)) * 3072 + h * 192;
    const u16* VTg = VT + (size_t)bh * 192 * 1024;

    unsigned koff[3], voff[3];
#pragma unroll
    for (int i = 0; i < 3; ++i) {
        int ch = i * 256 + t;
        int kr = ch / 24, kc = ch % 24;
        koff[i] = kr * 3072 + (kc ^ (kr & 7)) * 8;
        int vr = ch >> 2, vc = ch & 3;
        voff[i] = vr * 1024 + (vc ^ ((vr >> 1) & 3)) * 8;   // period-8 swizzle
    }

#define STAGE_KV(kt) do {                                                         \
    int sl_ = (kt) % 3;                                                           \
    _Pragma("unroll")                                                             \
    for (int i = 0; i < 3; ++i) {                                                 \
        async16(Kg + koff[i] + (unsigned)(kt) * 98304u, lK + sl_ * 6144 + (i * 256 + w * 64) * 8); \
        async16(VTg + voff[i] + (unsigned)(kt) * 32u,   lV + sl_ * 6144 + (i * 256 + w * 64) * 8); \
    } } while (0)

    STAGE_KV(0);
    STAGE_KV(1);                               // 2-deep prefetch in flight

    bf16x8 aq[2][6];
#pragma unroll
    for (int rg = 0; rg < 2; ++rg)
#pragma unroll
        for (int cs = 0; cs < 6; ++cs)
            aq[rg][cs] = *(const bf16x8*)(Qg + (size_t)(rg * 16 + ql) * 3072
                                             + cs * 32 + g * 8);

    bf16x8 vone;
#pragma unroll
    for (int j = 0; j < 8; ++j) vone[j] = (short)0x3F80;

    f32x4 acc_o[2][12] = {};
    f32x4 acc_l[2] = {};                       // per-row lsum via ones-MFMA
    float m2[2] = {-1e30f, -1e30f};            // per-4-row-group running max
    u16* lPw = &lP[w * 1024];                  // [32][32], 16B-chunk XOR by (q>>2)&3
    const int pswz = (ql >> 2) & 3;

#pragma unroll 1
    for (int it = 0; it < 32; ++it) {
        if (it != 31) asm volatile("s_waitcnt vmcnt(6)" ::: "memory");
        else          asm volatile("s_waitcnt vmcnt(0)" ::: "memory");
        __builtin_amdgcn_s_barrier();
        if (it < 30) STAGE_KV(it + 2);

        const u16* sK = lK + (it % 3) * 6144;
        const u16* sV = lV + (it % 3) * 6144;

        f32x4 s[2][2] = {};
        __builtin_amdgcn_s_setprio(1);
#pragma unroll
        for (int kf = 0; kf < 2; ++kf) {
            const int krow = kf * 16 + ql;
#pragma unroll
            for (int cs = 0; cs < 6; ++cs) {
                bf16x8 bk = *(const bf16x8*)&sK[krow * 192 + ((cs * 4 + g) ^ (krow & 7)) * 8];
                s[0][kf] = __builtin_amdgcn_mfma_f32_16x16x32_bf16(aq[0][cs], bk, s[0][kf], 0, 0, 0);
                s[1][kf] = __builtin_amdgcn_mfma_f32_16x16x32_bf16(aq[1][cs], bk, s[1][kf], 0, 0, 0);
            }
        }
        __builtin_amdgcn_s_setprio(0);

#pragma unroll
        for (int rg = 0; rg < 2; ++rg) {
            float m = s[rg][0][0];
#pragma unroll
            for (int kf = 0; kf < 2; ++kf)
#pragma unroll
                for (int r = 0; r < 4; ++r) m = fmaxf(m, s[rg][kf][r]);
            float mx = dppmax16(m);
            bool need = mx > m2[rg] + 8.f;
            if (__any((int)need)) {
                float mn = fmaxf(m2[rg], mx);
                float fac = exp2f(m2[rg] - mn);
                m2[rg] = mn;
                acc_l[rg] *= fac;
#pragma unroll
                for (int df = 0; df < 12; ++df) acc_o[rg][df] *= fac;
            }
#pragma unroll
            for (int r = 0; r < 4; ++r) {
                int q = rg * 16 + g * 4 + r;
#pragma unroll
                for (int kf = 0; kf < 2; ++kf) {
                    float p = exp2f(s[rg][kf][r] - m2[rg]);   // bounded by 2^8
                    lPw[q * 32 + ((kf * 16 + ql) ^ (g << 3))] = f2bf_rz(p);
                }
            }
        }

        __builtin_amdgcn_s_setprio(1);
        {
            bf16x8 pa0 = *(const bf16x8*)&lPw[ql * 32 + ((g ^ pswz) << 3)];
            bf16x8 pa1 = *(const bf16x8*)&lPw[(16 + ql) * 32 + ((g ^ pswz) << 3)];
            acc_l[0] = __builtin_amdgcn_mfma_f32_16x16x32_bf16(pa0, vone, acc_l[0], 0, 0, 0);
            acc_l[1] = __builtin_amdgcn_mfma_f32_16x16x32_bf16(pa1, vone, acc_l[1], 0, 0, 0);
#pragma unroll
            for (int df = 0; df < 12; ++df) {
                const int vrow = df * 16 + ql;
                bf16x8 bv = *(const bf16x8*)&sV[vrow * 32 + ((g ^ ((vrow >> 1) & 3)) << 3)];
                acc_o[0][df] = __builtin_amdgcn_mfma_f32_16x16x32_bf16(pa0, bv, acc_o[0][df], 0, 0, 0);
                acc_o[1][df] = __builtin_amdgcn_mfma_f32_16x16x32_bf16(pa1, bv, acc_o[1][df], 0, 0, 0);
            }
        }
        __builtin_amdgcn_s_setprio(0);
    }

    u16* dst = comb + ((size_t)(b * 1024 + qt * 128 + w * 32)) * 3072 + h * 192;
#pragma unroll
    for (int rg = 0; rg < 2; ++rg)
#pragma unroll
        for (int r = 0; r < 4; ++r) {
            int q = rg * 16 + g * 4 + r;
            float invl = 1.0f / acc_l[rg][r];
#pragma unroll
            for (int df = 0; df < 12; ++df)
                dst[(size_t)q * 3072 + df * 16 + ql] = f2bf(acc_o[rg][df][r] * invl);
        }
#undef STAGE_KV
}

// ---------------- host ----------------
extern "C" void kernel_launch(void* const* d_in, const int* in_sizes, int n_in,
                              void* d_out, int out_size, void* d_ws, size_t ws_size,
                              hipStream_t stream) {
    const float* X  = (const float*)d_in[0];   // [8,3072,1024]
    const float* W1 = (const float*)d_in[1];   // [1024,3072]
    const float* W2 = (const float*)d_in[2];   // [3072,1024]
    const float* Bb = (const float*)d_in[3];   // [1024]

    char* ws = (char*)d_ws;
    u16* Xb   = (u16*)(ws);                          // 50,331,648 B ; reused as comb
    u16* W1bT = (u16*)(ws + 50331648);               //  6,291,456 B  [3072][1024]
    u16* W2bT = (u16*)(ws + 56623104);               //  6,291,456 B  [1024][3072]
    u16* QKVb = (u16*)(ws + 62914560);               // 150,994,944 B [24576][3072] (V third unused)
    u16* VT   = (u16*)(ws + 213909504);              // 50,331,648 B  [128][192][1024]
    u16* comb = Xb;                                  // [8192][3072]

    cast_kernel<<<2048, 256, 0, stream>>>(X, Xb, (8 * 3072 * 1024) / 4);
    wtrans_kernel<<<dim3(3072 / 64, 1024 / 64), 256, 0, stream>>>(W1, W1bT, 1024, 3072);
    wtrans_kernel<<<dim3(1024 / 64, 3072 / 64), 256, 0, stream>>>(W2, W2bT, 3072, 1024);
    // GEMM1 (QKV): pipelined 256^2 ring kernel; V-third -> VT transposed, Q-third pre-scaled
    gemm256_kernel<<<(24576 / 256) * (3072 / 256), 512, 0, stream>>>(
        Xb, W1bT, QKVb, VT, 24576, 3072, 1024);
    attn_kernel<<<1024, 256, 0, stream>>>(QKVb, VT, comb);
    gemm_bt_kernel<true><<<(8192 / 128) * (1024 / 128), 256, 0, stream>>>(
        comb, W2bT, d_out, Bb, nullptr, 8192, 1024, 3072);
}